// Round 10
// baseline (691.003 us; speedup 1.0000x reference)
//
#include <hip/hip_runtime.h>
#include <math.h>

#define NN 3072
#define NH 8
#define FO 64
#define FCAT 512
#define MAXDEG 128
#define ALPHA 0.2f

typedef __attribute__((ext_vector_type(8))) short bf16x8;
typedef __attribute__((ext_vector_type(4))) float f32x4;

static __device__ __forceinline__ unsigned short f2bf(float v) {
    union { float f; unsigned u; } x; x.f = v;
    unsigned r = x.u + 0x7fffu + ((x.u >> 16) & 1u);
    return (unsigned short)(r >> 16);
}
static __device__ __forceinline__ float bf2f(unsigned short b) {
    union { unsigned u; float f; } x; x.u = ((unsigned)b) << 16;
    return x.f;
}

// software grid barrier: monotone counter, release-add / spin / acquire
static __device__ __forceinline__ void gridbar(unsigned* bar, unsigned target) {
    __syncthreads();
    if (threadIdx.x == 0) {
        __threadfence();                      // agent release (L1 flush, L2 wb)
        atomicAdd(bar, 1u);                   // device-scope
        while (__hip_atomic_load(bar, __ATOMIC_RELAXED, __HIP_MEMORY_SCOPE_AGENT) < target) {
            __builtin_amdgcn_s_sleep(2);
        }
        __threadfence();                      // agent acquire (L1/L2 inv)
    }
    __syncthreads();
}

// Persistent kernel: prelude + 4 x (gemm_ee, attn_agg) with software grid barriers.
// Launched with nblk = occupancy * numCU (all blocks co-resident); grid-stride tasks.
__global__ __launch_bounds__(256, 2) void gat_all_k(
    const float* __restrict__ x, const float* __restrict__ adj,
    const float* __restrict__ W1, const float* __restrict__ W2,
    const float* __restrict__ W3, const float* __restrict__ W4,
    const float* __restrict__ a1, const float* __restrict__ a2,
    const float* __restrict__ a3, const float* __restrict__ a4,
    unsigned short* __restrict__ Ah, unsigned short* __restrict__ Al,
    unsigned short* __restrict__ Wth, unsigned short* __restrict__ Wtl,
    int* __restrict__ deg, int* __restrict__ nbr,
    float* __restrict__ WhF, float* __restrict__ esrc, float* __restrict__ edst,
    float* __restrict__ out, int nblk, unsigned* bar)
{
    __shared__ __align__(16) unsigned char smem[40960];

    const int b = blockIdx.x;
    const int tid = threadIdx.x;
    const int lane = tid & 63;
    const int ws = tid >> 6;
    unsigned ph = 0;

    // ================= phase 0: prelude =================
    for (int t = b; t < 1232; t += nblk) {
        if (t < 256) {
            int base = t * 1536 + tid;
            #pragma unroll
            for (int i = 0; i < 6; ++i) {
                int idx = base + i * 256;
                float v = x[idx];
                unsigned short hb = f2bf(v);
                Ah[idx] = hb;
                Al[idx] = f2bf(v - bf2f(hb));
            }
        } else if (t < 464) {
            int tw = t - 256;
            float (*tt)[65] = (float(*)[65])smem;
            const float* W; int K; int local; size_t obase;
            if (tw < 16)       { W = W1; K = 128; local = tw;       obase = 0; }
            else if (tw < 80)  { W = W2; K = 512; local = tw - 16;  obase = 65536; }
            else if (tw < 144) { W = W3; K = 512; local = tw - 80;  obase = 327680; }
            else               { W = W4; K = 512; local = tw - 144; obase = 589824; }
            int nkt = K >> 6;
            int h = local / nkt, kt = local - h * nkt;
            int k0 = kt * 64;
            for (int idx = tid; idx < 4096; idx += 256) {
                int r = idx >> 6, c = idx & 63;
                tt[r][c] = W[(size_t)h * K * FO + (size_t)(k0 + r) * FO + c];
            }
            __syncthreads();
            for (int idx = tid; idx < 4096; idx += 256) {
                int o = idx >> 6, kk = idx & 63;
                float v = tt[kk][o];
                unsigned short hb = f2bf(v);
                size_t dst = obase + (size_t)(h * FO + o) * K + k0 + kk;
                Wth[dst] = hb;
                Wtl[dst] = f2bf(v - bf2f(hb));
            }
            __syncthreads();
        } else {
            int row = (t - 464) * 4 + ws;
            const float* arow = adj + (size_t)row * NN;
            int count = 0;
            for (int base = 0; base < NN; base += 64) {
                float v = arow[base + lane];
                unsigned long long m = __ballot(v > 0.0f);
                if (v > 0.0f) {
                    int pos = count + __popcll(m & ((1ull << lane) - 1ull));
                    if (pos < MAXDEG) nbr[(size_t)row * MAXDEG + pos] = base + lane;
                }
                count += __popcll(m);
            }
            if (lane == 0) deg[row] = count < MAXDEG ? count : MAXDEG;
        }
    }
    gridbar(bar, ++ph * (unsigned)nblk);

    // ================= layer loop =================
    const float* aps[4] = {a1, a2, a3, a4};
    const size_t woff[4] = {0, 65536, 327680, 589824};
    int K = 128;

    for (int L = 0; L < 4; ++L) {
        const unsigned short* Bh = Wth + woff[L];
        const unsigned short* Bl = Wtl + woff[L];
        const float* av_g = aps[L];

        // ---- GEMM + ee phase: 384 tasks ----
        for (int t = b; t < 384; t += nblk) {
            const int h = t & 7;
            const int r0 = (t >> 3) * 64;
            typedef float CsT[68];
            unsigned short* As_ = (unsigned short*)smem;
            unsigned short* Bs_ = (unsigned short*)(smem + 20480);
            CsT* Cs = reinterpret_cast<CsT*>(smem);

            const int wr = ws >> 1, wc = ws & 1;
            const int lr = lane & 15, lg = lane >> 4;

            const unsigned short* Bhh = Bh + (size_t)h * FO * K;
            const unsigned short* Bll = Bl + (size_t)h * FO * K;

            const int row0 = tid >> 3, cq0 = tid & 7;
            const int off0 = row0 * 80 + ((cq0 ^ (row0 & 7)) * 8);
            const size_t gA0 = (size_t)(r0 + row0) * K + cq0 * 8;
            const size_t gA1 = gA0 + (size_t)32 * K;
            const size_t gB0 = (size_t)row0 * K + cq0 * 8;
            const size_t gB1 = gB0 + (size_t)32 * K;

            bf16x8 ra0h, ra0l, ra1h, ra1l, rb0h, rb0l, rb1h, rb1l;

            auto loadg = [&](int k0) {
                ra0h = *(const bf16x8*)(Ah + gA0 + k0);
                ra0l = *(const bf16x8*)(Al + gA0 + k0);
                ra1h = *(const bf16x8*)(Ah + gA1 + k0);
                ra1l = *(const bf16x8*)(Al + gA1 + k0);
                rb0h = *(const bf16x8*)(Bhh + gB0 + k0);
                rb0l = *(const bf16x8*)(Bll + gB0 + k0);
                rb1h = *(const bf16x8*)(Bhh + gB1 + k0);
                rb1l = *(const bf16x8*)(Bll + gB1 + k0);
            };
            auto store_lds = [&]() {
                *(bf16x8*)&As_[off0] = ra0h;
                *(bf16x8*)&As_[off0 + 2560] = ra1h;
                *(bf16x8*)&As_[5120 + off0] = ra0l;
                *(bf16x8*)&As_[5120 + off0 + 2560] = ra1l;
                *(bf16x8*)&Bs_[off0] = rb0h;
                *(bf16x8*)&Bs_[off0 + 2560] = rb1h;
                *(bf16x8*)&Bs_[5120 + off0] = rb0l;
                *(bf16x8*)&Bs_[5120 + off0 + 2560] = rb1l;
            };

            f32x4 acc[2][2];
            #pragma unroll
            for (int i = 0; i < 2; ++i)
                #pragma unroll
                for (int j = 0; j < 2; ++j) acc[i][j] = (f32x4){0.f, 0.f, 0.f, 0.f};

            auto mfma_phase = [&]() {
                #pragma unroll
                for (int ks = 0; ks < 2; ++ks) {
                    bf16x8 ah[2], al[2], bh[2], bl[2];
                    int cq = ks * 4 + lg;
                    #pragma unroll
                    for (int i = 0; i < 2; ++i) {
                        int row = wr * 32 + i * 16 + lr;
                        int offa = row * 80 + ((cq ^ (row & 7)) * 8);
                        ah[i] = *(const bf16x8*)&As_[offa];
                        al[i] = *(const bf16x8*)&As_[5120 + offa];
                        int col = wc * 32 + i * 16 + lr;
                        int offb = col * 80 + ((cq ^ (col & 7)) * 8);
                        bh[i] = *(const bf16x8*)&Bs_[offb];
                        bl[i] = *(const bf16x8*)&Bs_[5120 + offb];
                    }
                    #pragma unroll
                    for (int i = 0; i < 2; ++i)
                        #pragma unroll
                        for (int j = 0; j < 2; ++j) {
                            acc[i][j] = __builtin_amdgcn_mfma_f32_16x16x32_bf16(ah[i], bh[j], acc[i][j], 0, 0, 0);
                            acc[i][j] = __builtin_amdgcn_mfma_f32_16x16x32_bf16(ah[i], bl[j], acc[i][j], 0, 0, 0);
                            acc[i][j] = __builtin_amdgcn_mfma_f32_16x16x32_bf16(al[i], bh[j], acc[i][j], 0, 0, 0);
                        }
                }
            };

            loadg(0);
            store_lds();
            __syncthreads();
            for (int k0 = 64; k0 < K; k0 += 64) {
                loadg(k0);
                mfma_phase();
                __syncthreads();
                store_lds();
                __syncthreads();
            }
            mfma_phase();
            __syncthreads();

            #pragma unroll
            for (int i = 0; i < 2; ++i)
                #pragma unroll
                for (int j = 0; j < 2; ++j)
                    #pragma unroll
                    for (int r = 0; r < 4; ++r)
                        Cs[wr * 32 + i * 16 + lg * 4 + r][wc * 32 + j * 16 + lr] = acc[i][j][r];
            __syncthreads();

            #pragma unroll
            for (int it = 0; it < 4; ++it) {
                int idx = tid + it * 256;
                int r = idx >> 4, c4 = idx & 15;
                *(float4*)&WhF[(size_t)(r0 + r) * FCAT + h * FO + c4 * 4] = *(float4*)&Cs[r][c4 * 4];
            }

            {
                int r = tid >> 2, sub = tid & 3;
                const float* av = av_g + h * 2 * FO;
                float s = 0.0f, dd = 0.0f;
                #pragma unroll
                for (int k = 0; k < 16; ++k) {
                    float v = Cs[r][sub * 16 + k];
                    s = fmaf(v, av[sub * 16 + k], s);
                    dd = fmaf(v, av[FO + sub * 16 + k], dd);
                }
                s += __shfl_xor(s, 1); s += __shfl_xor(s, 2);
                dd += __shfl_xor(dd, 1); dd += __shfl_xor(dd, 2);
                if (sub == 0) {
                    esrc[h * NN + r0 + r] = s;
                    edst[h * NN + r0 + r] = dd;
                }
            }
            __syncthreads();
        }
        gridbar(bar, ++ph * (unsigned)nblk);

        // ---- attention + aggregation phase: per-wave tasks, h-major ----
        {
            float (*pbuf)[MAXDEG] = (float(*)[MAXDEG])smem;
            int (*jbuf)[MAXDEG] = (int(*)[MAXDEG])(smem + 4 * MAXDEG * sizeof(float));
            const int write_f32 = (L == 3);
            for (int wt = b * 4 + ws; wt < NH * NN; wt += nblk * 4) {
                const int h = wt / NN;
                const int n = wt - h * NN;
                const int d = deg[n];
                const int* nb = nbr + (size_t)n * MAXDEG;
                const float es = esrc[h * NN + n];
                const float* ed = edst + h * NN;

                for (int tt = lane; tt < d; tt += 64) {
                    int j = nb[tt];
                    float e = es + ed[j];
                    e = (e > 0.0f) ? e : ALPHA * e;
                    jbuf[ws][tt] = j;
                    pbuf[ws][tt] = e;
                }
                float lm = -3.0e38f;
                for (int tt = lane; tt < d; tt += 64) lm = fmaxf(lm, pbuf[ws][tt]);
                #pragma unroll
                for (int off = 32; off; off >>= 1) lm = fmaxf(lm, __shfl_xor(lm, off));
                float lsum = 0.0f;
                for (int tt = lane; tt < d; tt += 64) {
                    float pv = __expf(pbuf[ws][tt] - lm);
                    pbuf[ws][tt] = pv;
                    lsum += pv;
                }
                #pragma unroll
                for (int off = 32; off; off >>= 1) lsum += __shfl_xor(lsum, off);

                const float* whb = WhF + h * FO + lane;
                float q0 = 0.f, q1 = 0.f, q2 = 0.f, q3 = 0.f;
                int tt = 0;
                for (; tt + 3 < d; tt += 4) {
                    q0 = fmaf(pbuf[ws][tt + 0], whb[(size_t)jbuf[ws][tt + 0] * FCAT], q0);
                    q1 = fmaf(pbuf[ws][tt + 1], whb[(size_t)jbuf[ws][tt + 1] * FCAT], q1);
                    q2 = fmaf(pbuf[ws][tt + 2], whb[(size_t)jbuf[ws][tt + 2] * FCAT], q2);
                    q3 = fmaf(pbuf[ws][tt + 3], whb[(size_t)jbuf[ws][tt + 3] * FCAT], q3);
                }
                for (; tt < d; ++tt)
                    q0 = fmaf(pbuf[ws][tt], whb[(size_t)jbuf[ws][tt] * FCAT], q0);
                float acc = (q0 + q1) + (q2 + q3);
                acc /= lsum;
                float r = (acc > 0.0f) ? acc : (__expf(acc) - 1.0f);  // ELU
                size_t idx = (size_t)n * FCAT + h * FO + lane;
                if (write_f32) {
                    out[idx] = r;
                } else {
                    unsigned short hb = f2bf(r);
                    Ah[idx] = hb;
                    Al[idx] = f2bf(r - bf2f(hb));
                }
            }
        }
        if (L < 3) gridbar(bar, ++ph * (unsigned)nblk);
        K = FCAT;
    }
}

extern "C" void kernel_launch(void* const* d_in, const int* in_sizes, int n_in,
                              void* d_out, int out_size, void* d_ws, size_t ws_size,
                              hipStream_t stream) {
    const float* x   = (const float*)d_in[0];
    const float* adj = (const float*)d_in[1];
    const float* W1 = (const float*)d_in[2];
    const float* a1 = (const float*)d_in[3];
    const float* W2 = (const float*)d_in[4];
    const float* a2 = (const float*)d_in[5];
    const float* W3 = (const float*)d_in[6];
    const float* a3 = (const float*)d_in[7];
    const float* W4 = (const float*)d_in[8];
    const float* a4 = (const float*)d_in[9];
    float* out = (float*)d_out;

    char* p = (char*)d_ws;
    unsigned* bar = (unsigned*)p;    p += 256;
    int* deg = (int*)p;              p += (size_t)NN * sizeof(int);
    int* nbr = (int*)p;              p += (size_t)NN * MAXDEG * sizeof(int);
    unsigned short* Ah = (unsigned short*)p; p += (size_t)NN * FCAT * 2;
    unsigned short* Al = (unsigned short*)p; p += (size_t)NN * FCAT * 2;
    float* WhF = (float*)p;          p += (size_t)NN * FCAT * sizeof(float);
    unsigned short* Wth = (unsigned short*)p; p += (size_t)851968 * 2;
    unsigned short* Wtl = (unsigned short*)p; p += (size_t)851968 * 2;
    float* esrc = (float*)p;         p += (size_t)NN * NH * sizeof(float);
    float* edst = (float*)p;         p += (size_t)NN * NH * sizeof(float);

    hipMemsetAsync(bar, 0, sizeof(unsigned), stream);

    int ncu = 0, occ = 0;
    if (hipDeviceGetAttribute(&ncu, hipDeviceAttributeMultiprocessorCount, 0) != hipSuccess || ncu < 1)
        ncu = 256;
    if (hipOccupancyMaxActiveBlocksPerMultiprocessor(&occ, gat_all_k, 256, 0) != hipSuccess || occ < 1)
        occ = 1;
    int nblk = occ * ncu;
    if (nblk > 1024) nblk = 1024;

    gat_all_k<<<nblk, 256, 0, stream>>>(x, adj, W1, W2, W3, W4, a1, a2, a3, a4,
                                        Ah, Al, Wth, Wtl, deg, nbr, WhF, esrc, edst,
                                        out, nblk, bar);
}